// Round 17
// baseline (226.636 us; speedup 1.0000x reference)
//
#include <hip/hip_runtime.h>
#include <hip/hip_bf16.h>
#include <math.h>

#define DIMC 1024
#define NHEAD 16
#define HDIM 64
#define MPAD 12288   // 12224 padded: 96*128, 64*192, 48*256

using bf16x8 = __attribute__((ext_vector_type(8))) short;
using f32x4  = __attribute__((ext_vector_type(4))) float;
using f32x16 = __attribute__((ext_vector_type(16))) float;

__device__ inline ushort f2bf(float f) {          // round-to-nearest-even
    uint u = __float_as_uint(f);
    u += 0x7fffu + ((u >> 16) & 1u);
    return (ushort)(u >> 16);
}
__device__ inline float bf2f(ushort h) { return __uint_as_float(((uint)h) << 16); }

__device__ inline uint pkbf(float a, float b) {   // pack 2 f32 -> 2 bf16 (lo=a)
    __hip_bfloat162 t = __float22bfloat162_rn(float2{a, b});
    return *reinterpret_cast<uint*>(&t);
}

__device__ inline void gload_lds16(const ushort* g, ushort* l) {
    __builtin_amdgcn_global_load_lds(
        (const __attribute__((address_space(1))) uint*)g,
        (__attribute__((address_space(3))) uint*)l, 16, 0, 0);
}

// ---------------------------------------------------------------------------
// QKV GEMM v2 (r13/r16 verified: ~95us, MfmaUtil 34%, 2 blocks/CU):
// 128x192 tile, BK=64, 8 waves, LDS 80KB, grid 1536 = 3 exact rounds.
// ---------------------------------------------------------------------------
__global__ __launch_bounds__(512, 4) void gemm192(
    const ushort* __restrict__ A, const ushort* __restrict__ Bt,
    const float* __restrict__ bq, const float* __restrict__ bk,
    const float* __restrict__ bv,
    ushort* __restrict__ qb, ushort* __restrict__ kb, ushort* __restrict__ vb,
    int M)
{
    __shared__ ushort lds[2][(128 + 192) * 64];   // A at 0, B at 128*64 ushorts

    const int bid = blockIdx.x;
    const int xcd = bid & 7;
    const int j   = bid >> 3;                     // 0..191
    const int mt  = xcd * 12 + (j % 12);          // 0..95
    const int nt  = j / 12;                       // 0..15
    const int row0 = mt * 128;
    const int col0 = nt * 192;

    const int t512 = threadIdx.x;
    const int w    = t512 >> 6;
    const int lane = t512 & 63;
    const int wm   = w >> 2;                      // 0..1
    const int wn   = w & 3;                       // 0..3
    const int l15  = lane & 15;
    const int kh   = lane >> 4;                   // 0..3

    const int a0row = (w < 4) ? (w * 8) : (64 + (w - 4) * 8);   // qr0 rows
    const int a1row = a0row + 32;                                // qr1 rows

    auto stage = [&](int buf, int kt, int mat, int relRow) {
        const int o   = relRow * 128 + lane * 16;
        const int row = o >> 7;
        const int kb_ = (o & 127) ^ ((row & 7) << 4);
        const ushort* src = (mat ? Bt + (size_t)(col0 + row) * DIMC
                                 : A  + (size_t)(row0 + row) * DIMC)
                            + kt * 64 + (kb_ >> 1);
        gload_lds16(src, &lds[buf][0] + mat * (128 * 64) + relRow * 64);
    };
    auto rdA = [&](int buf, int rf, int ks) -> bf16x8 {
        const int row = wm * 64 + rf * 16 + l15;
        const int ad  = (row * 128 + ks * 64 + kh * 16) ^ ((row & 7) << 4);
        return *(const bf16x8*)(&lds[buf][0] + (ad >> 1));
    };
    auto rdB = [&](int buf, int n, int ks) -> bf16x8 {
        const int row = wn * 48 + n * 16 + l15;
        const int ad  = (row * 128 + ks * 64 + kh * 16) ^ ((row & 7) << 4);
        return *(const bf16x8*)(&lds[buf][128 * 64] + (ad >> 1));
    };

    f32x4 acc[4][3] = {};
    bf16x8 af[2][2];
    bf16x8 bf[3][2];

    stage(0, 0, 0, a0row);
    stage(0, 0, 1, w * 24);
    stage(0, 0, 1, w * 24 + 8);
    stage(0, 0, 1, w * 24 + 16);
    stage(0, 0, 0, a1row);

    const int NT = DIMC / 64;    // 16
    for (int t = 0; t < NT; ++t) {
        const int cur = t & 1;
        const int nxt = cur ^ 1;
        const int tn  = (t + 1 < NT) ? (t + 1) : (NT - 1);

        // -------- phase 0: qr0 (rf0,1) x all 48 cols --------
        asm volatile("s_waitcnt vmcnt(1)" ::: "memory");
        __builtin_amdgcn_s_barrier();
        __builtin_amdgcn_sched_barrier(0);
        #pragma unroll
        for (int rf = 0; rf < 2; ++rf)
            #pragma unroll
            for (int ks = 0; ks < 2; ++ks)
                af[rf][ks] = rdA(cur, rf, ks);
        #pragma unroll
        for (int n = 0; n < 3; ++n)
            #pragma unroll
            for (int ks = 0; ks < 2; ++ks)
                bf[n][ks] = rdB(cur, n, ks);
        stage(nxt, tn, 0, a0row);
        stage(nxt, tn, 1, w * 24);
        stage(nxt, tn, 1, w * 24 + 8);
        stage(nxt, tn, 1, w * 24 + 16);
        __builtin_amdgcn_s_setprio(1);
        #pragma unroll
        for (int rf = 0; rf < 2; ++rf)
            #pragma unroll
            for (int n = 0; n < 3; ++n)
                #pragma unroll
                for (int ks = 0; ks < 2; ++ks)
                    acc[rf][n] = __builtin_amdgcn_mfma_f32_16x16x32_bf16(
                        af[rf][ks], bf[n][ks], acc[rf][n], 0, 0, 0);
        __builtin_amdgcn_s_setprio(0);

        // -------- phase 1: qr1 (rf2,3) x all 48 cols --------
        asm volatile("s_waitcnt vmcnt(4)" ::: "memory");
        __builtin_amdgcn_s_barrier();
        __builtin_amdgcn_sched_barrier(0);
        #pragma unroll
        for (int rf = 0; rf < 2; ++rf)
            #pragma unroll
            for (int ks = 0; ks < 2; ++ks)
                af[rf][ks] = rdA(cur, 2 + rf, ks);
        stage(nxt, tn, 0, a1row);
        __builtin_amdgcn_s_setprio(1);
        #pragma unroll
        for (int rf = 0; rf < 2; ++rf)
            #pragma unroll
            for (int n = 0; n < 3; ++n)
                #pragma unroll
                for (int ks = 0; ks < 2; ++ks)
                    acc[2 + rf][n] = __builtin_amdgcn_mfma_f32_16x16x32_bf16(
                        af[rf][ks], bf[n][ks], acc[2 + rf][n], 0, 0, 0);
        __builtin_amdgcn_s_setprio(0);
    }

    #pragma unroll
    for (int n = 0; n < 3; ++n) {
        const int cg = col0 + wn * 48 + n * 16 + l15;
        const int s  = cg >> 10;
        const int cb = cg & 1023;
        const float bb = ((s == 0) ? bq : (s == 1) ? bk : bv)[cb];
        ushort* op     = (s == 0) ? qb : (s == 1) ? kb : vb;
        #pragma unroll
        for (int i = 0; i < 4; ++i) {
            #pragma unroll
            for (int r = 0; r < 4; ++r) {
                const int gr = row0 + wm * 64 + i * 16 + kh * 4 + r;
                if (gr < M)
                    op[(size_t)gr * DIMC + cb] = f2bf(acc[i][n][r] + bb);
            }
        }
    }
}

// ---------------------------------------------------------------------------
// Final GEMM v4 (r16 verified): 192x128 tile, symmetric counted ledger,
// 2 blocks/CU, grid 512 = 1 exact round.
// ---------------------------------------------------------------------------
__global__ __launch_bounds__(512, 4) void gemmF(
    const ushort* __restrict__ A, const ushort* __restrict__ Bt,
    const float* __restrict__ bias, float* __restrict__ C, int M)
{
    __shared__ ushort lds[2][(192 + 128) * 64];   // A at 0, B at 192*64 ushorts

    const int bid = blockIdx.x;
    const int xcd = bid & 7;
    const int j   = bid >> 3;                     // 0..63
    const int mt  = xcd * 8 + (j % 8);            // 0..63
    const int nt  = j / 8;                        // 0..7
    const int row0 = mt * 192;
    const int col0 = nt * 128;

    const int t512 = threadIdx.x;
    const int w    = t512 >> 6;
    const int lane = t512 & 63;
    const int wm   = w >> 1;                      // 0..3
    const int wn   = w & 1;                       // 0..1
    const int l15  = lane & 15;
    const int kh   = lane >> 4;                   // 0..3

    auto stage = [&](int buf, int kt, int mat, int relRow) {
        const int o   = relRow * 128 + lane * 16;
        const int row = o >> 7;
        const int kb_ = (o & 127) ^ ((row & 7) << 4);
        const ushort* src = (mat ? Bt + (size_t)(col0 + row) * DIMC
                                 : A  + (size_t)(row0 + row) * DIMC)
                            + kt * 64 + (kb_ >> 1);
        gload_lds16(src, &lds[buf][0] + mat * (192 * 64) + relRow * 64);
    };
    auto rdA = [&](int buf, int rf, int ks) -> bf16x8 {
        const int row = wm * 48 + rf * 16 + l15;
        const int ad  = (row * 128 + ks * 64 + kh * 16) ^ ((row & 7) << 4);
        return *(const bf16x8*)(&lds[buf][0] + (ad >> 1));
    };
    auto rdB = [&](int buf, int n, int ks) -> bf16x8 {
        const int row = wn * 64 + n * 16 + l15;
        const int ad  = (row * 128 + ks * 64 + kh * 16) ^ ((row & 7) << 4);
        return *(const bf16x8*)(&lds[buf][192 * 64] + (ad >> 1));
    };

    f32x4 acc[3][4] = {};
    bf16x8 af[2];           // current row-frag (2 ks)
    bf16x8 bf[4][2];        // all 4 col-frags, read once per K-tile

    const int aP0 = wm * 48 + wn * 8;        // phase-0 A chunk
    const int aP1 = aP0 + 16;                // phase-1 A chunk
    const int aP2 = aP0 + 32;                // phase-2 A chunk

    // prologue: tile 0 -> buf 0, slot order B0 B1 a0 a1 a2
    stage(0, 0, 1, w * 16);
    stage(0, 0, 1, w * 16 + 8);
    stage(0, 0, 0, aP0);
    stage(0, 0, 0, aP1);
    stage(0, 0, 0, aP2);

    const int NT = DIMC / 64;    // 16
    for (int t = 0; t < NT; ++t) {
        const int cur = t & 1;
        const int nxt = cur ^ 1;
        const int tn  = (t + 1 < NT) ? (t + 1) : (NT - 1);   // last iter: dead restage

        // -------- phase 0: rf0 x all 64 cols --------
        asm volatile("s_waitcnt vmcnt(2)" ::: "memory");
        __builtin_amdgcn_s_barrier();
        __builtin_amdgcn_sched_barrier(0);
        #pragma unroll
        for (int ks = 0; ks < 2; ++ks)
            af[ks] = rdA(cur, 0, ks);
        #pragma unroll
        for (int n = 0; n < 4; ++n)
            #pragma unroll
            for (int ks = 0; ks < 2; ++ks)
                bf[n][ks] = rdB(cur, n, ks);
        stage(nxt, tn, 1, w * 16);
        stage(nxt, tn, 1, w * 16 + 8);
        stage(nxt, tn, 0, aP0);
        __builtin_amdgcn_s_setprio(1);
        #pragma unroll
        for (int n = 0; n < 4; ++n)
            #pragma unroll
            for (int ks = 0; ks < 2; ++ks)
                acc[0][n] = __builtin_amdgcn_mfma_f32_16x16x32_bf16(
                    af[ks], bf[n][ks], acc[0][n], 0, 0, 0);
        __builtin_amdgcn_s_setprio(0);

        // -------- phase 1: rf1 --------
        asm volatile("s_waitcnt vmcnt(4)" ::: "memory");
        __builtin_amdgcn_s_barrier();
        __builtin_amdgcn_sched_barrier(0);
        #pragma unroll
        for (int ks = 0; ks < 2; ++ks)
            af[ks] = rdA(cur, 1, ks);
        stage(nxt, tn, 0, aP1);
        __builtin_amdgcn_s_setprio(1);
        #pragma unroll
        for (int n = 0; n < 4; ++n)
            #pragma unroll
            for (int ks = 0; ks < 2; ++ks)
                acc[1][n] = __builtin_amdgcn_mfma_f32_16x16x32_bf16(
                    af[ks], bf[n][ks], acc[1][n], 0, 0, 0);
        __builtin_amdgcn_s_setprio(0);

        // -------- phase 2: rf2 --------
        asm volatile("s_waitcnt vmcnt(4)" ::: "memory");
        __builtin_amdgcn_s_barrier();
        __builtin_amdgcn_sched_barrier(0);
        #pragma unroll
        for (int ks = 0; ks < 2; ++ks)
            af[ks] = rdA(cur, 2, ks);
        stage(nxt, tn, 0, aP2);
        __builtin_amdgcn_s_setprio(1);
        #pragma unroll
        for (int n = 0; n < 4; ++n)
            #pragma unroll
            for (int ks = 0; ks < 2; ++ks)
                acc[2][n] = __builtin_amdgcn_mfma_f32_16x16x32_bf16(
                    af[ks], bf[n][ks], acc[2][n], 0, 0, 0);
        __builtin_amdgcn_s_setprio(0);
    }

    // epilogue
    #pragma unroll
    for (int n = 0; n < 4; ++n) {
        const int c  = col0 + wn * 64 + n * 16 + l15;
        const float bb = bias[c];
        #pragma unroll
        for (int i = 0; i < 3; ++i) {
            #pragma unroll
            for (int r = 0; r < 4; ++r) {
                const int gr = row0 + wm * 48 + i * 16 + kh * 4 + r;
                if (gr < M)
                    C[(size_t)gr * DIMC + c] = acc[i][n][r] + bb;
            }
        }
    }
}

// ---------------------------------------------------------------------------
// Fused preprocessing: z=0..3 -> transpose+cvt W[z]; z=4 -> cvt+pad x.
// ---------------------------------------------------------------------------
__global__ __launch_bounds__(256) void prep_all(
    const float* __restrict__ x, ushort* __restrict__ xb, int nvalid, int ntot,
    const float* __restrict__ W0, const float* __restrict__ W1,
    const float* __restrict__ W2, const float* __restrict__ W3,
    ushort* __restrict__ T0, ushort* __restrict__ T1,
    ushort* __restrict__ T2, ushort* __restrict__ T3)
{
    __shared__ float tile[32][33];
    const int z = blockIdx.z;
    if (z == 4) {
        const int bidf  = blockIdx.y * 32 + blockIdx.x;      // 0..1023
        const int start = bidf * 256 + threadIdx.x;
        const int stride = 1024 * 256;
        for (int i = start; i < ntot / 4; i += stride) {
            const int e = i * 4;
            ushort4 o;
            if (e < nvalid) {
                const float4 f = *(const float4*)(x + e);
                o.x = f2bf(f.x); o.y = f2bf(f.y); o.z = f2bf(f.z); o.w = f2bf(f.w);
            } else { o.x = o.y = o.z = o.w = 0; }
            *(ushort4*)(xb + e) = o;
        }
        return;
    }
    const float* W = (z == 0) ? W0 : (z == 1) ? W1 : (z == 2) ? W2 : W3;
    ushort*      T = (z == 0) ? T0 : (z == 1) ? T1 : (z == 2) ? T2 : T3;
    const int tx = threadIdx.x & 31;
    const int ty = threadIdx.x >> 5;
    const int n0 = blockIdx.x * 32;
    const int k0 = blockIdx.y * 32;
    #pragma unroll
    for (int i = 0; i < 32; i += 8)
        tile[ty + i][tx] = W[(size_t)(k0 + ty + i) * DIMC + n0 + tx];
    __syncthreads();
    #pragma unroll
    for (int i = 0; i < 32; i += 8)
        T[(size_t)(n0 + ty + i) * DIMC + k0 + tx] = f2bf(tile[tx][ty + i]);
}

// ---------------------------------------------------------------------------
// MFMA flash attention v3: one 256-thread block per (b,h).  exp2-domain
// softmax: Q pre-scaled by (1/sqrt(1024))*log2(e), all exps are single
// v_exp_f32 (exp2f) -- no per-score mul by log2e.  Otherwise r12-verified.
// ---------------------------------------------------------------------------
__global__ __launch_bounds__(256) void attn_mfma(
    const ushort* __restrict__ qg, const ushort* __restrict__ kg,
    const ushort* __restrict__ vg, ushort* __restrict__ og,
    const int* __restrict__ lens, int B)
{
    __shared__ ushort Kt[2][64 * 64];   // swizzled K tiles (8KB each)
    __shared__ ushort Vt[64 * 68];      // V^T, row stride 68 ushorts

    const int i   = blockIdx.x;
    const int xcd = i & 7;
    const int j   = i >> 3;
    const int bh  = xcd * (B * 2) + j;
    const int h   = bh & 15;
    const int b   = bh >> 4;

    const int tid  = threadIdx.x;
    const int qt   = tid >> 6;
    const int lane = tid & 63;

    const int myl = (lane < B) ? lens[lane] : 0;
    int inc = myl;
    #pragma unroll
    for (int d = 1; d < 64; d <<= 1) {
        const int nb = __shfl_up(inc, d);
        if (lane >= d) inc += nb;
    }
    const int off = __shfl(inc, b) - __shfl(myl, b);
    const int L   = __shfl(myl, b);
    const int ntk = (L + 63) >> 6;
    const bool active = (qt * 64 < L);

    const int l31 = lane & 31;
    const int hi  = lane >> 5;

    // Q fragments with scale*(log2 e) folded in: scores land in log2 domain.
    const float QSCALE = 0.03125f * 1.44269504f;
    bf16x8 qf[2][4];
    if (active) {
        #pragma unroll
        for (int qn = 0; qn < 2; ++qn) {
            const size_t row = (size_t)(off + min(qt * 64 + qn * 32 + l31, L - 1));
            #pragma unroll
            for (int ks = 0; ks < 4; ++ks) {
                union { uint4 u4; ushort us[8]; bf16x8 v; } tmp;
                tmp.u4 = *(const uint4*)(qg + row * DIMC + h * HDIM + ks * 16 + hi * 8);
                #pragma unroll
                for (int e = 0; e < 8; ++e)
                    tmp.us[e] = f2bf(bf2f(tmp.us[e]) * QSCALE);
                qf[qn][ks] = tmp.v;
            }
        }
    }

    auto stageK = [&](int tt, int buf) {
        #pragma unroll
        for (int u0 = 0; u0 < 2; ++u0) {
            const int u   = tid + u0 * 256;
            const int o   = u * 16;
            const int row = o >> 7;
            const int kb_ = (o & 127) ^ ((row & 7) << 4);
            const ushort* src = kg + (size_t)(off + min(tt * 64 + row, L - 1)) * DIMC
                                + h * HDIM + (kb_ >> 1);
            gload_lds16(src, &Kt[buf][0] + u * 8);
        }
    };

    const int pr   = lane & 7;
    const int doct = lane >> 3;
    const int d0v  = doct * 8;
    uint4 v0, v1;
    auto loadV = [&](int tt) {
        const int k0 = tt * 64 + qt * 16 + 2 * pr;
        v0 = *(const uint4*)(vg + (size_t)(off + min(k0,     L - 1)) * DIMC + h * HDIM + d0v);
        v1 = *(const uint4*)(vg + (size_t)(off + min(k0 + 1, L - 1)) * DIMC + h * HDIM + d0v);
    };

    stageK(0, 0);
    loadV(0);

    f32x16 o[2][2] = {};
    float mst[2] = {-1e30f, -1e30f};
    float lst[2] = {0.f, 0.f};

    for (int t = 0; t < ntk; ++t) {
        const int cur = t & 1;
        const int j0  = t * 64;
        const int tn  = (t + 1 < ntk) ? (t + 1) : (ntk - 1);

        stageK(tn, cur ^ 1);
        asm volatile("s_waitcnt vmcnt(2)" ::: "memory");
        __builtin_amdgcn_s_barrier();
        __builtin_amdgcn_sched_barrier(0);

        f32x16 s[2][2] = {};
        if (active) {
            bf16x8 kf[2][4];
            #pragma unroll
            for (int km = 0; km < 2; ++km) {
                const int row = km * 32 + l31;
                #pragma unroll
                for (int ks = 0; ks < 4; ++ks) {
                    const int ad = (row * 128 + ks * 32 + hi * 16) ^ ((row & 7) << 4);
                    kf[km][ks] = *(const bf16x8*)(&Kt[cur][0] + (ad >> 1));
                }
            }
            __builtin_amdgcn_s_setprio(1);
            #pragma unroll
            for (int km = 0; km < 2; ++km)
                #pragma unroll
                for (int qn = 0; qn < 2; ++qn)
                    #pragma unroll
                    for (int ks = 0; ks < 4; ++ks)
                        s[km][qn] = __builtin_amdgcn_mfma_f32_32x32x16_bf16(
                            kf[km][ks], qf[qn][ks], s[km][qn], 0, 0, 0);
            __builtin_amdgcn_s_setprio(0);
        }

        {
            const uint a4[4] = {v0.x, v0.y, v0.z, v0.w};
            const uint b4[4] = {v1.x, v1.y, v1.z, v1.w};
            const int  col   = qt * 16 + 2 * pr;
            #pragma unroll
            for (int jj = 0; jj < 4; ++jj) {
                const uint lo  = (a4[jj] & 0xffffu) | (b4[jj] << 16);
                const uint hi2 = (a4[jj] >> 16) | (b4[jj] & 0xffff0000u);
                *(uint*)&Vt[(d0v + 2 * jj)     * 68 + col] = lo;
                *(uint*)&Vt[(d0v + 2 * jj + 1) * 68 + col] = hi2;
            }
        }
        if (t + 1 < ntk) loadV(t + 1);

        if (active) {
            const bool fullTile = (j0 + 64 <= L);
            float tmv[2];
            #pragma unroll
            for (int qn = 0; qn < 2; ++qn) {
                float tm = -1e30f;
                if (fullTile) {
                    #pragma unroll
                    for (int km = 0; km < 2; ++km)
                        #pragma unroll
                        for (int r = 0; r < 16; ++r)
                            tm = fmaxf(tm, s[km][qn][r]);
                } else {
                    #pragma unroll
                    for (int km = 0; km < 2; ++km)
                        #pragma unroll
                        for (int r = 0; r < 16; ++r) {
                            const int key = j0 + km * 32 + (r & 3) + 8 * (r >> 2) + 4 * hi;
                            float sv = s[km][qn][r];
                            sv = (key < L) ? sv : -1e30f;
                            s[km][qn][r] = sv;
                            tm = fmaxf(tm, sv);
                        }
                }
                tm = fmaxf(tm, __shfl_xor(tm, 32));
                tmv[qn] = tm;
            }

            // defer-max in log2 units: skip rescale while p <= 2^4
            const bool need = (tmv[0] > mst[0] + 4.f) || (tmv[1] > mst[1] + 4.f);
            if (__any(need)) {
                #pragma unroll
                for (int qn = 0; qn < 2; ++qn) {
                    const float nm = fmaxf(mst[qn], tmv[qn]);
                    const float corr = exp2f(mst[qn] - nm);
                    mst[qn] = nm;
                    lst[qn] *= corr;
                    #pragma unroll
                    for (int dm = 0; dm < 2; ++dm)
                        #pragma unroll
                        for (int r = 0; r < 16; ++r)
                            o[dm][qn][r] *= corr;
                }
            }
            #pragma unroll
            for (int qn = 0; qn < 2; ++qn) {
                float ls = 0.f;
                #pragma unroll
                for (int km = 0; km < 2; ++km)
                    #pragma unroll
                    for (int r = 0; r < 16; ++r) {
                        const float p = exp2f(s[km][qn][r] - mst[qn]);
                        s[km][qn][r] = p;
                        ls += p;
                    }
                ls += __shfl_xor(ls, 32);
                lst[qn] += ls;
            }
        }

        asm volatile("s_waitcnt lgkmcnt(0)" ::: "memory");
        __builtin_amdgcn_s_barrier();
        __builtin_amdgcn_sched_barrier(0);

        if (active) {
            #pragma unroll
            for (int kspv = 0; kspv < 4; ++kspv) {
                const int km = kspv >> 1;
                const int sb = kspv & 1;

                bf16x8 Afr[2];
                #pragma unroll
                for (int dm = 0; dm < 2; ++dm) {
                    const int d = dm * 32 + l31;
                    const uint2 p0 = *(const uint2*)&Vt[d * 68 + kspv * 16 + hi * 8];
                    const uint2 p1 = *(const uint2*)&Vt[d * 68 + kspv * 16 + hi * 8 + 4];
                    union { uint u[4]; bf16x8 v; } aa;
                    aa.u[0] = p0.x; aa.u[1] = p0.y; aa.u[2] = p1.x; aa.u[3] = p1.y;
                    Afr[dm] = aa.v;
                }

                bf16x8 Bfr[2];
                #pragma unroll
                for (int qn = 0; qn < 2; ++qn) {
                    const uint X0 = pkbf(s[km][qn][8 * sb + 0], s[km][qn][8 * sb + 1]);
                    const uint X1 = pkbf(s[km][qn][8 * sb + 2], s[km][qn][8 * sb + 3]);
                    const uint Y0 = pkbf(s[km][qn][8 * sb + 4], s[km][qn][8 * sb + 5]);
                    const uint Y1 = pkbf(s[km][qn][8 * sb + 6], s[km][qn][8 * sb + 7]);
                    const uint sx0 = (uint)__shfl_xor((int)X0, 32);
                    const uint sx1 = (uint)__shfl_xor((int)X1, 32);
                    const uint sy0 = (uint)__shfl_xor((int)Y0, 32);
                    const uint sy1 = (uint)__shfl_xor((int)Y1, 32);
                    union { uint u[4]; bf16x8 v; } bb;
                    bb.u[0] = hi ? sy0 : X0;
                    bb.u[1] = hi ? sy1 : X1;
                    bb.u[2] = hi ? Y0 : sx0;
                    bb.u[3] = hi ? Y1 : sx1;
                    Bfr[qn] = bb.v;
                }

                __builtin_amdgcn_s_setprio(1);
                #pragma unroll
                for (int dm = 0; dm < 2; ++dm)
                    #pragma unroll
                    for (int qn = 0; qn < 2; ++qn)
                        o[dm][qn] = __builtin_amdgcn_mfma_f32_32x32x16_bf16(
                            Afr[dm], Bfr[qn], o[dm][qn], 0, 0, 0);
                __builtin_amdgcn_s_setprio(0);
            }
        }
    }

    if (active) {
        #pragma unroll
        for (int qn = 0; qn < 2; ++qn) {
            const int q = qt * 64 + qn * 32 + l31;
            if (q < L) {
                const float inv = 1.f / lst[qn];
                ushort* orow = og + (size_t)(off + q) * DIMC + h * HDIM;
                #pragma unroll
                for (int dm = 0; dm < 2; ++dm)
                    #pragma unroll
                    for (int bq2 = 0; bq2 < 4; ++bq2) {
                        const int r0 = 4 * bq2;
                        uint2 st;
                        st.x = pkbf(o[dm][qn][r0 + 0] * inv, o[dm][qn][r0 + 1] * inv);
                        st.y = pkbf(o[dm][qn][r0 + 2] * inv, o[dm][qn][r0 + 3] * inv);
                        *(uint2*)(orow + dm * 32 + 8 * bq2 + 4 * hi) = st;
                    }
            }
        }
    }
}

// ---------------------------------------------------------------------------
extern "C" void kernel_launch(void* const* d_in, const int* in_sizes, int n_in,
                              void* d_out, int out_size, void* d_ws, size_t ws_size,
                              hipStream_t stream)
{
    const float* x   = (const float*)d_in[0];
    const float* Wq  = (const float*)d_in[1];
    const float* bq  = (const float*)d_in[2];
    const float* Wk  = (const float*)d_in[3];
    const float* bk  = (const float*)d_in[4];
    const float* Wv  = (const float*)d_in[5];
    const float* bv  = (const float*)d_in[6];
    const float* Wu  = (const float*)d_in[7];
    const float* bu  = (const float*)d_in[8];
    const int*  lens = (const int*)d_in[9];

    const int N = in_sizes[0] / DIMC;    // 12224
    const int B = in_sizes[9];           // 64

    ushort* xb  = (ushort*)d_ws;                         // MPAD*1024 bf16
    ushort* wtq = xb  + (size_t)MPAD * DIMC;             // 3 contiguous = Wt_cat
    ushort* wtk = wtq + (size_t)DIMC * DIMC;
    ushort* wtv = wtk + (size_t)DIMC * DIMC;
    ushort* wtu = wtv + (size_t)DIMC * DIMC;
    ushort* kb  = wtu + (size_t)DIMC * DIMC;             // N*1024 bf16
    ushort* vb  = kb  + (size_t)N * DIMC;                // N*1024 bf16
    ushort* qb  = (ushort*)d_out;                        // q lives in d_out (bf16)
    ushort* ob  = xb;                                    // attn out reuses xb

    // fused preprocessing: 4 weight transposes + x cvt/pad in one launch
    prep_all<<<dim3(32, 32, 5), 256, 0, stream>>>(
        x, xb, N * DIMC, MPAD * DIMC, Wq, Wk, Wv, Wu, wtq, wtk, wtv, wtu);

    // fused QKV: 96 mt x 16 nt = 1536 blocks = 3 exact rounds at 2 blocks/CU
    gemm192<<<1536, 512, 0, stream>>>(xb, wtq, bq, bk, bv, qb, kb, vb, N);

    // attention: one 4-wave block per (b,h)
    attn_mfma<<<dim3(B * NHEAD), dim3(256), 0, stream>>>(qb, kb, vb, ob, lens, B);

    // final: 64 mt x 8 nt = 512 blocks = 1 exact round at 2 blocks/CU
    gemmF<<<512, 512, 0, stream>>>(ob, wtu, bu, (float*)d_out, N);
}

// Round 18
// 217.174 us; speedup vs baseline: 1.0436x; 1.0436x over previous
//
#include <hip/hip_runtime.h>
#include <hip/hip_bf16.h>
#include <math.h>

#define DIMC 1024
#define NHEAD 16
#define HDIM 64
#define MPAD 12288   // 12224 padded: 96*128, 64*192, 48*256

using bf16x8 = __attribute__((ext_vector_type(8))) short;
using f32x4  = __attribute__((ext_vector_type(4))) float;
using f32x16 = __attribute__((ext_vector_type(16))) float;

__device__ inline ushort f2bf(float f) {          // round-to-nearest-even
    uint u = __float_as_uint(f);
    u += 0x7fffu + ((u >> 16) & 1u);
    return (ushort)(u >> 16);
}
__device__ inline float bf2f(ushort h) { return __uint_as_float(((uint)h) << 16); }

__device__ inline uint pkbf(float a, float b) {   // pack 2 f32 -> 2 bf16 (lo=a)
    __hip_bfloat162 t = __float22bfloat162_rn(float2{a, b});
    return *reinterpret_cast<uint*>(&t);
}

__device__ inline void gload_lds16(const ushort* g, ushort* l) {
    __builtin_amdgcn_global_load_lds(
        (const __attribute__((address_space(1))) uint*)g,
        (__attribute__((address_space(3))) uint*)l, 16, 0, 0);
}

// ---------------------------------------------------------------------------
// QKV GEMM v2 (r13/r16 verified: ~95us, MfmaUtil 34%, 2 blocks/CU):
// 128x192 tile, BK=64, 8 waves, LDS 80KB, grid 1536 = 3 exact rounds.
// ---------------------------------------------------------------------------
__global__ __launch_bounds__(512, 4) void gemm192(
    const ushort* __restrict__ A, const ushort* __restrict__ Bt,
    const float* __restrict__ bq, const float* __restrict__ bk,
    const float* __restrict__ bv,
    ushort* __restrict__ qb, ushort* __restrict__ kb, ushort* __restrict__ vb,
    int M)
{
    __shared__ ushort lds[2][(128 + 192) * 64];   // A at 0, B at 128*64 ushorts

    const int bid = blockIdx.x;
    const int xcd = bid & 7;
    const int j   = bid >> 3;                     // 0..191
    const int mt  = xcd * 12 + (j % 12);          // 0..95
    const int nt  = j / 12;                       // 0..15
    const int row0 = mt * 128;
    const int col0 = nt * 192;

    const int t512 = threadIdx.x;
    const int w    = t512 >> 6;
    const int lane = t512 & 63;
    const int wm   = w >> 2;                      // 0..1
    const int wn   = w & 3;                       // 0..3
    const int l15  = lane & 15;
    const int kh   = lane >> 4;                   // 0..3

    const int a0row = (w < 4) ? (w * 8) : (64 + (w - 4) * 8);   // qr0 rows
    const int a1row = a0row + 32;                                // qr1 rows

    auto stage = [&](int buf, int kt, int mat, int relRow) {
        const int o   = relRow * 128 + lane * 16;
        const int row = o >> 7;
        const int kb_ = (o & 127) ^ ((row & 7) << 4);
        const ushort* src = (mat ? Bt + (size_t)(col0 + row) * DIMC
                                 : A  + (size_t)(row0 + row) * DIMC)
                            + kt * 64 + (kb_ >> 1);
        gload_lds16(src, &lds[buf][0] + mat * (128 * 64) + relRow * 64);
    };
    auto rdA = [&](int buf, int rf, int ks) -> bf16x8 {
        const int row = wm * 64 + rf * 16 + l15;
        const int ad  = (row * 128 + ks * 64 + kh * 16) ^ ((row & 7) << 4);
        return *(const bf16x8*)(&lds[buf][0] + (ad >> 1));
    };
    auto rdB = [&](int buf, int n, int ks) -> bf16x8 {
        const int row = wn * 48 + n * 16 + l15;
        const int ad  = (row * 128 + ks * 64 + kh * 16) ^ ((row & 7) << 4);
        return *(const bf16x8*)(&lds[buf][128 * 64] + (ad >> 1));
    };

    f32x4 acc[4][3] = {};
    bf16x8 af[2][2];
    bf16x8 bf[3][2];

    stage(0, 0, 0, a0row);
    stage(0, 0, 1, w * 24);
    stage(0, 0, 1, w * 24 + 8);
    stage(0, 0, 1, w * 24 + 16);
    stage(0, 0, 0, a1row);

    const int NT = DIMC / 64;    // 16
    for (int t = 0; t < NT; ++t) {
        const int cur = t & 1;
        const int nxt = cur ^ 1;
        const int tn  = (t + 1 < NT) ? (t + 1) : (NT - 1);

        // -------- phase 0: qr0 (rf0,1) x all 48 cols --------
        asm volatile("s_waitcnt vmcnt(1)" ::: "memory");
        __builtin_amdgcn_s_barrier();
        __builtin_amdgcn_sched_barrier(0);
        #pragma unroll
        for (int rf = 0; rf < 2; ++rf)
            #pragma unroll
            for (int ks = 0; ks < 2; ++ks)
                af[rf][ks] = rdA(cur, rf, ks);
        #pragma unroll
        for (int n = 0; n < 3; ++n)
            #pragma unroll
            for (int ks = 0; ks < 2; ++ks)
                bf[n][ks] = rdB(cur, n, ks);
        stage(nxt, tn, 0, a0row);
        stage(nxt, tn, 1, w * 24);
        stage(nxt, tn, 1, w * 24 + 8);
        stage(nxt, tn, 1, w * 24 + 16);
        __builtin_amdgcn_s_setprio(1);
        #pragma unroll
        for (int rf = 0; rf < 2; ++rf)
            #pragma unroll
            for (int n = 0; n < 3; ++n)
                #pragma unroll
                for (int ks = 0; ks < 2; ++ks)
                    acc[rf][n] = __builtin_amdgcn_mfma_f32_16x16x32_bf16(
                        af[rf][ks], bf[n][ks], acc[rf][n], 0, 0, 0);
        __builtin_amdgcn_s_setprio(0);

        // -------- phase 1: qr1 (rf2,3) x all 48 cols --------
        asm volatile("s_waitcnt vmcnt(4)" ::: "memory");
        __builtin_amdgcn_s_barrier();
        __builtin_amdgcn_sched_barrier(0);
        #pragma unroll
        for (int rf = 0; rf < 2; ++rf)
            #pragma unroll
            for (int ks = 0; ks < 2; ++ks)
                af[rf][ks] = rdA(cur, 2 + rf, ks);
        stage(nxt, tn, 0, a1row);
        __builtin_amdgcn_s_setprio(1);
        #pragma unroll
        for (int rf = 0; rf < 2; ++rf)
            #pragma unroll
            for (int n = 0; n < 3; ++n)
                #pragma unroll
                for (int ks = 0; ks < 2; ++ks)
                    acc[2 + rf][n] = __builtin_amdgcn_mfma_f32_16x16x32_bf16(
                        af[rf][ks], bf[n][ks], acc[2 + rf][n], 0, 0, 0);
        __builtin_amdgcn_s_setprio(0);
    }

    #pragma unroll
    for (int n = 0; n < 3; ++n) {
        const int cg = col0 + wn * 48 + n * 16 + l15;
        const int s  = cg >> 10;
        const int cb = cg & 1023;
        const float bb = ((s == 0) ? bq : (s == 1) ? bk : bv)[cb];
        ushort* op     = (s == 0) ? qb : (s == 1) ? kb : vb;
        #pragma unroll
        for (int i = 0; i < 4; ++i) {
            #pragma unroll
            for (int r = 0; r < 4; ++r) {
                const int gr = row0 + wm * 64 + i * 16 + kh * 4 + r;
                if (gr < M)
                    op[(size_t)gr * DIMC + cb] = f2bf(acc[i][n][r] + bb);
            }
        }
    }
}

// ---------------------------------------------------------------------------
// Final GEMM v4 (r16 verified): 192x128 tile, symmetric counted ledger,
// 2 blocks/CU, grid 512 = 1 exact round.
// ---------------------------------------------------------------------------
__global__ __launch_bounds__(512, 4) void gemmF(
    const ushort* __restrict__ A, const ushort* __restrict__ Bt,
    const float* __restrict__ bias, float* __restrict__ C, int M)
{
    __shared__ ushort lds[2][(192 + 128) * 64];   // A at 0, B at 192*64 ushorts

    const int bid = blockIdx.x;
    const int xcd = bid & 7;
    const int j   = bid >> 3;                     // 0..63
    const int mt  = xcd * 8 + (j % 8);            // 0..63
    const int nt  = j / 8;                        // 0..7
    const int row0 = mt * 192;
    const int col0 = nt * 128;

    const int t512 = threadIdx.x;
    const int w    = t512 >> 6;
    const int lane = t512 & 63;
    const int wm   = w >> 1;                      // 0..3
    const int wn   = w & 1;                       // 0..1
    const int l15  = lane & 15;
    const int kh   = lane >> 4;                   // 0..3

    auto stage = [&](int buf, int kt, int mat, int relRow) {
        const int o   = relRow * 128 + lane * 16;
        const int row = o >> 7;
        const int kb_ = (o & 127) ^ ((row & 7) << 4);
        const ushort* src = (mat ? Bt + (size_t)(col0 + row) * DIMC
                                 : A  + (size_t)(row0 + row) * DIMC)
                            + kt * 64 + (kb_ >> 1);
        gload_lds16(src, &lds[buf][0] + mat * (192 * 64) + relRow * 64);
    };
    auto rdA = [&](int buf, int rf, int ks) -> bf16x8 {
        const int row = wm * 48 + rf * 16 + l15;
        const int ad  = (row * 128 + ks * 64 + kh * 16) ^ ((row & 7) << 4);
        return *(const bf16x8*)(&lds[buf][0] + (ad >> 1));
    };
    auto rdB = [&](int buf, int n, int ks) -> bf16x8 {
        const int row = wn * 64 + n * 16 + l15;
        const int ad  = (row * 128 + ks * 64 + kh * 16) ^ ((row & 7) << 4);
        return *(const bf16x8*)(&lds[buf][192 * 64] + (ad >> 1));
    };

    f32x4 acc[3][4] = {};
    bf16x8 af[2];           // current row-frag (2 ks)
    bf16x8 bf[4][2];        // all 4 col-frags, read once per K-tile

    const int aP0 = wm * 48 + wn * 8;        // phase-0 A chunk
    const int aP1 = aP0 + 16;                // phase-1 A chunk
    const int aP2 = aP0 + 32;                // phase-2 A chunk

    // prologue: tile 0 -> buf 0, slot order B0 B1 a0 a1 a2
    stage(0, 0, 1, w * 16);
    stage(0, 0, 1, w * 16 + 8);
    stage(0, 0, 0, aP0);
    stage(0, 0, 0, aP1);
    stage(0, 0, 0, aP2);

    const int NT = DIMC / 64;    // 16
    for (int t = 0; t < NT; ++t) {
        const int cur = t & 1;
        const int nxt = cur ^ 1;
        const int tn  = (t + 1 < NT) ? (t + 1) : (NT - 1);   // last iter: dead restage

        // -------- phase 0: rf0 x all 64 cols --------
        asm volatile("s_waitcnt vmcnt(2)" ::: "memory");
        __builtin_amdgcn_s_barrier();
        __builtin_amdgcn_sched_barrier(0);
        #pragma unroll
        for (int ks = 0; ks < 2; ++ks)
            af[ks] = rdA(cur, 0, ks);
        #pragma unroll
        for (int n = 0; n < 4; ++n)
            #pragma unroll
            for (int ks = 0; ks < 2; ++ks)
                bf[n][ks] = rdB(cur, n, ks);
        stage(nxt, tn, 1, w * 16);
        stage(nxt, tn, 1, w * 16 + 8);
        stage(nxt, tn, 0, aP0);
        __builtin_amdgcn_s_setprio(1);
        #pragma unroll
        for (int n = 0; n < 4; ++n)
            #pragma unroll
            for (int ks = 0; ks < 2; ++ks)
                acc[0][n] = __builtin_amdgcn_mfma_f32_16x16x32_bf16(
                    af[ks], bf[n][ks], acc[0][n], 0, 0, 0);
        __builtin_amdgcn_s_setprio(0);

        // -------- phase 1: rf1 --------
        asm volatile("s_waitcnt vmcnt(4)" ::: "memory");
        __builtin_amdgcn_s_barrier();
        __builtin_amdgcn_sched_barrier(0);
        #pragma unroll
        for (int ks = 0; ks < 2; ++ks)
            af[ks] = rdA(cur, 1, ks);
        stage(nxt, tn, 0, aP1);
        __builtin_amdgcn_s_setprio(1);
        #pragma unroll
        for (int n = 0; n < 4; ++n)
            #pragma unroll
            for (int ks = 0; ks < 2; ++ks)
                acc[1][n] = __builtin_amdgcn_mfma_f32_16x16x32_bf16(
                    af[ks], bf[n][ks], acc[1][n], 0, 0, 0);
        __builtin_amdgcn_s_setprio(0);

        // -------- phase 2: rf2 --------
        asm volatile("s_waitcnt vmcnt(4)" ::: "memory");
        __builtin_amdgcn_s_barrier();
        __builtin_amdgcn_sched_barrier(0);
        #pragma unroll
        for (int ks = 0; ks < 2; ++ks)
            af[ks] = rdA(cur, 2, ks);
        stage(nxt, tn, 0, aP2);
        __builtin_amdgcn_s_setprio(1);
        #pragma unroll
        for (int n = 0; n < 4; ++n)
            #pragma unroll
            for (int ks = 0; ks < 2; ++ks)
                acc[2][n] = __builtin_amdgcn_mfma_f32_16x16x32_bf16(
                    af[ks], bf[n][ks], acc[2][n], 0, 0, 0);
        __builtin_amdgcn_s_setprio(0);
    }

    // epilogue
    #pragma unroll
    for (int n = 0; n < 4; ++n) {
        const int c  = col0 + wn * 64 + n * 16 + l15;
        const float bb = bias[c];
        #pragma unroll
        for (int i = 0; i < 3; ++i) {
            #pragma unroll
            for (int r = 0; r < 4; ++r) {
                const int gr = row0 + wm * 48 + i * 16 + kh * 4 + r;
                if (gr < M)
                    C[(size_t)gr * DIMC + c] = acc[i][n][r] + bb;
            }
        }
    }
}

// ---------------------------------------------------------------------------
// Fused preprocessing: z=0..3 -> transpose+cvt W[z]; z=4 -> cvt+pad x.
// ---------------------------------------------------------------------------
__global__ __launch_bounds__(256) void prep_all(
    const float* __restrict__ x, ushort* __restrict__ xb, int nvalid, int ntot,
    const float* __restrict__ W0, const float* __restrict__ W1,
    const float* __restrict__ W2, const float* __restrict__ W3,
    ushort* __restrict__ T0, ushort* __restrict__ T1,
    ushort* __restrict__ T2, ushort* __restrict__ T3)
{
    __shared__ float tile[32][33];
    const int z = blockIdx.z;
    if (z == 4) {
        const int bidf  = blockIdx.y * 32 + blockIdx.x;      // 0..1023
        const int start = bidf * 256 + threadIdx.x;
        const int stride = 1024 * 256;
        for (int i = start; i < ntot / 4; i += stride) {
            const int e = i * 4;
            ushort4 o;
            if (e < nvalid) {
                const float4 f = *(const float4*)(x + e);
                o.x = f2bf(f.x); o.y = f2bf(f.y); o.z = f2bf(f.z); o.w = f2bf(f.w);
            } else { o.x = o.y = o.z = o.w = 0; }
            *(ushort4*)(xb + e) = o;
        }
        return;
    }
    const float* W = (z == 0) ? W0 : (z == 1) ? W1 : (z == 2) ? W2 : W3;
    ushort*      T = (z == 0) ? T0 : (z == 1) ? T1 : (z == 2) ? T2 : T3;
    const int tx = threadIdx.x & 31;
    const int ty = threadIdx.x >> 5;
    const int n0 = blockIdx.x * 32;
    const int k0 = blockIdx.y * 32;
    #pragma unroll
    for (int i = 0; i < 32; i += 8)
        tile[ty + i][tx] = W[(size_t)(k0 + ty + i) * DIMC + n0 + tx];
    __syncthreads();
    #pragma unroll
    for (int i = 0; i < 32; i += 8)
        T[(size_t)(n0 + ty + i) * DIMC + k0 + tx] = f2bf(tile[tx][ty + i]);
}

// ---------------------------------------------------------------------------
// MFMA flash attention v4: one 256-thread block per (b,h), IDENTITY block
// mapping.  r12-r17's XCD remap put contiguous bh (= sorted-by-length b)
// chunks on each XCD -> 1.39x work imbalance; since the q-tile merge (r12)
// removed any cross-block K/V reuse, identity order (16 heads of each image
// round-robin across XCDs) load-balances with zero locality cost.
// exp2-domain softmax (r17 neutral-verified).
// ---------------------------------------------------------------------------
__global__ __launch_bounds__(256) void attn_mfma(
    const ushort* __restrict__ qg, const ushort* __restrict__ kg,
    const ushort* __restrict__ vg, ushort* __restrict__ og,
    const int* __restrict__ lens, int B)
{
    __shared__ ushort Kt[2][64 * 64];   // swizzled K tiles (8KB each)
    __shared__ ushort Vt[64 * 68];      // V^T, row stride 68 ushorts

    const int bh = blockIdx.x;          // identity mapping (load balance)
    const int h  = bh & 15;
    const int b  = bh >> 4;

    const int tid  = threadIdx.x;
    const int qt   = tid >> 6;
    const int lane = tid & 63;

    const int myl = (lane < B) ? lens[lane] : 0;
    int inc = myl;
    #pragma unroll
    for (int d = 1; d < 64; d <<= 1) {
        const int nb = __shfl_up(inc, d);
        if (lane >= d) inc += nb;
    }
    const int off = __shfl(inc, b) - __shfl(myl, b);
    const int L   = __shfl(myl, b);
    const int ntk = (L + 63) >> 6;
    const bool active = (qt * 64 < L);

    const int l31 = lane & 31;
    const int hi  = lane >> 5;

    // Q fragments with scale*(log2 e) folded in: scores land in log2 domain.
    const float QSCALE = 0.03125f * 1.44269504f;
    bf16x8 qf[2][4];
    if (active) {
        #pragma unroll
        for (int qn = 0; qn < 2; ++qn) {
            const size_t row = (size_t)(off + min(qt * 64 + qn * 32 + l31, L - 1));
            #pragma unroll
            for (int ks = 0; ks < 4; ++ks) {
                union { uint4 u4; ushort us[8]; bf16x8 v; } tmp;
                tmp.u4 = *(const uint4*)(qg + row * DIMC + h * HDIM + ks * 16 + hi * 8);
                #pragma unroll
                for (int e = 0; e < 8; ++e)
                    tmp.us[e] = f2bf(bf2f(tmp.us[e]) * QSCALE);
                qf[qn][ks] = tmp.v;
            }
        }
    }

    auto stageK = [&](int tt, int buf) {
        #pragma unroll
        for (int u0 = 0; u0 < 2; ++u0) {
            const int u   = tid + u0 * 256;
            const int o   = u * 16;
            const int row = o >> 7;
            const int kb_ = (o & 127) ^ ((row & 7) << 4);
            const ushort* src = kg + (size_t)(off + min(tt * 64 + row, L - 1)) * DIMC
                                + h * HDIM + (kb_ >> 1);
            gload_lds16(src, &Kt[buf][0] + u * 8);
        }
    };

    const int pr   = lane & 7;
    const int doct = lane >> 3;
    const int d0v  = doct * 8;
    uint4 v0, v1;
    auto loadV = [&](int tt) {
        const int k0 = tt * 64 + qt * 16 + 2 * pr;
        v0 = *(const uint4*)(vg + (size_t)(off + min(k0,     L - 1)) * DIMC + h * HDIM + d0v);
        v1 = *(const uint4*)(vg + (size_t)(off + min(k0 + 1, L - 1)) * DIMC + h * HDIM + d0v);
    };

    stageK(0, 0);
    loadV(0);

    f32x16 o[2][2] = {};
    float mst[2] = {-1e30f, -1e30f};
    float lst[2] = {0.f, 0.f};

    for (int t = 0; t < ntk; ++t) {
        const int cur = t & 1;
        const int j0  = t * 64;
        const int tn  = (t + 1 < ntk) ? (t + 1) : (ntk - 1);

        stageK(tn, cur ^ 1);
        asm volatile("s_waitcnt vmcnt(2)" ::: "memory");
        __builtin_amdgcn_s_barrier();
        __builtin_amdgcn_sched_barrier(0);

        f32x16 s[2][2] = {};
        if (active) {
            bf16x8 kf[2][4];
            #pragma unroll
            for (int km = 0; km < 2; ++km) {
                const int row = km * 32 + l31;
                #pragma unroll
                for (int ks = 0; ks < 4; ++ks) {
                    const int ad = (row * 128 + ks * 32 + hi * 16) ^ ((row & 7) << 4);
                    kf[km][ks] = *(const bf16x8*)(&Kt[cur][0] + (ad >> 1));
                }
            }
            __builtin_amdgcn_s_setprio(1);
            #pragma unroll
            for (int km = 0; km < 2; ++km)
                #pragma unroll
                for (int qn = 0; qn < 2; ++qn)
                    #pragma unroll
                    for (int ks = 0; ks < 4; ++ks)
                        s[km][qn] = __builtin_amdgcn_mfma_f32_32x32x16_bf16(
                            kf[km][ks], qf[qn][ks], s[km][qn], 0, 0, 0);
            __builtin_amdgcn_s_setprio(0);
        }

        {
            const uint a4[4] = {v0.x, v0.y, v0.z, v0.w};
            const uint b4[4] = {v1.x, v1.y, v1.z, v1.w};
            const int  col   = qt * 16 + 2 * pr;
            #pragma unroll
            for (int jj = 0; jj < 4; ++jj) {
                const uint lo  = (a4[jj] & 0xffffu) | (b4[jj] << 16);
                const uint hi2 = (a4[jj] >> 16) | (b4[jj] & 0xffff0000u);
                *(uint*)&Vt[(d0v + 2 * jj)     * 68 + col] = lo;
                *(uint*)&Vt[(d0v + 2 * jj + 1) * 68 + col] = hi2;
            }
        }
        if (t + 1 < ntk) loadV(t + 1);

        if (active) {
            const bool fullTile = (j0 + 64 <= L);
            float tmv[2];
            #pragma unroll
            for (int qn = 0; qn < 2; ++qn) {
                float tm = -1e30f;
                if (fullTile) {
                    #pragma unroll
                    for (int km = 0; km < 2; ++km)
                        #pragma unroll
                        for (int r = 0; r < 16; ++r)
                            tm = fmaxf(tm, s[km][qn][r]);
                } else {
                    #pragma unroll
                    for (int km = 0; km < 2; ++km)
                        #pragma unroll
                        for (int r = 0; r < 16; ++r) {
                            const int key = j0 + km * 32 + (r & 3) + 8 * (r >> 2) + 4 * hi;
                            float sv = s[km][qn][r];
                            sv = (key < L) ? sv : -1e30f;
                            s[km][qn][r] = sv;
                            tm = fmaxf(tm, sv);
                        }
                }
                tm = fmaxf(tm, __shfl_xor(tm, 32));
                tmv[qn] = tm;
            }

            // defer-max in log2 units: skip rescale while p <= 2^4
            const bool need = (tmv[0] > mst[0] + 4.f) || (tmv[1] > mst[1] + 4.f);
            if (__any(need)) {
                #pragma unroll
                for (int qn = 0; qn < 2; ++qn) {
                    const float nm = fmaxf(mst[qn], tmv[qn]);
                    const float corr = exp2f(mst[qn] - nm);
                    mst[qn] = nm;
                    lst[qn] *= corr;
                    #pragma unroll
                    for (int dm = 0; dm < 2; ++dm)
                        #pragma unroll
                        for (int r = 0; r < 16; ++r)
                            o[dm][qn][r] *= corr;
                }
            }
            #pragma unroll
            for (int qn = 0; qn < 2; ++qn) {
                float ls = 0.f;
                #pragma unroll
                for (int km = 0; km < 2; ++km)
                    #pragma unroll
                    for (int r = 0; r < 16; ++r) {
                        const float p = exp2f(s[km][qn][r] - mst[qn]);
                        s[km][qn][r] = p;
                        ls += p;
                    }
                ls += __shfl_xor(ls, 32);
                lst[qn] += ls;
            }
        }

        asm volatile("s_waitcnt lgkmcnt(0)" ::: "memory");
        __builtin_amdgcn_s_barrier();
        __builtin_amdgcn_sched_barrier(0);

        if (active) {
            #pragma unroll
            for (int kspv = 0; kspv < 4; ++kspv) {
                const int km = kspv >> 1;
                const int sb = kspv & 1;

                bf16x8 Afr[2];
                #pragma unroll
                for (int dm = 0; dm < 2; ++dm) {
                    const int d = dm * 32 + l31;
                    const uint2 p0 = *(const uint2*)&Vt[d * 68 + kspv * 16 + hi * 8];
                    const uint2 p1 = *(const uint2*)&Vt[d * 68 + kspv * 16 + hi * 8 + 4];
                    union { uint u[4]; bf16x8 v; } aa;
                    aa.u[0] = p0.x; aa.u[1] = p0.y; aa.u[2] = p1.x; aa.u[3] = p1.y;
                    Afr[dm] = aa.v;
                }

                bf16x8 Bfr[2];
                #pragma unroll
                for (int qn = 0; qn < 2; ++qn) {
                    const uint X0 = pkbf(s[km][qn][8 * sb + 0], s[km][qn][8 * sb + 1]);
                    const uint X1 = pkbf(s[km][qn][8 * sb + 2], s[km][qn][8 * sb + 3]);
                    const uint Y0 = pkbf(s[km][qn][8 * sb + 4], s[km][qn][8 * sb + 5]);
                    const uint Y1 = pkbf(s[km][qn][8 * sb + 6], s[km][qn][8 * sb + 7]);
                    const uint sx0 = (uint)__shfl_xor((int)X0, 32);
                    const uint sx1 = (uint)__shfl_xor((int)X1, 32);
                    const uint sy0 = (uint)__shfl_xor((int)Y0, 32);
                    const uint sy1 = (uint)__shfl_xor((int)Y1, 32);
                    union { uint u[4]; bf16x8 v; } bb;
                    bb.u[0] = hi ? sy0 : X0;
                    bb.u[1] = hi ? sy1 : X1;
                    bb.u[2] = hi ? Y0 : sx0;
                    bb.u[3] = hi ? Y1 : sx1;
                    Bfr[qn] = bb.v;
                }

                __builtin_amdgcn_s_setprio(1);
                #pragma unroll
                for (int dm = 0; dm < 2; ++dm)
                    #pragma unroll
                    for (int qn = 0; qn < 2; ++qn)
                        o[dm][qn] = __builtin_amdgcn_mfma_f32_32x32x16_bf16(
                            Afr[dm], Bfr[qn], o[dm][qn], 0, 0, 0);
                __builtin_amdgcn_s_setprio(0);
            }
        }
    }

    if (active) {
        #pragma unroll
        for (int qn = 0; qn < 2; ++qn) {
            const int q = qt * 64 + qn * 32 + l31;
            if (q < L) {
                const float inv = 1.f / lst[qn];
                ushort* orow = og + (size_t)(off + q) * DIMC + h * HDIM;
                #pragma unroll
                for (int dm = 0; dm < 2; ++dm)
                    #pragma unroll
                    for (int bq2 = 0; bq2 < 4; ++bq2) {
                        const int r0 = 4 * bq2;
                        uint2 st;
                        st.x = pkbf(o[dm][qn][r0 + 0] * inv, o[dm][qn][r0 + 1] * inv);
                        st.y = pkbf(o[dm][qn][r0 + 2] * inv, o[dm][qn][r0 + 3] * inv);
                        *(uint2*)(orow + dm * 32 + 8 * bq2 + 4 * hi) = st;
                    }
            }
        }
    }
}

// ---------------------------------------------------------------------------
extern "C" void kernel_launch(void* const* d_in, const int* in_sizes, int n_in,
                              void* d_out, int out_size, void* d_ws, size_t ws_size,
                              hipStream_t stream)
{
    const float* x   = (const float*)d_in[0];
    const float* Wq  = (const float*)d_in[1];
    const float* bq  = (const float*)d_in[2];
    const float* Wk  = (const float*)d_in[3];
    const float* bk  = (const float*)d_in[4];
    const float* Wv  = (const float*)d_in[5];
    const float* bv  = (const float*)d_in[6];
    const float* Wu  = (const float*)d_in[7];
    const float* bu  = (const float*)d_in[8];
    const int*  lens = (const int*)d_in[9];

    const int N = in_sizes[0] / DIMC;    // 12224
    const int B = in_sizes[9];           // 64

    ushort* xb  = (ushort*)d_ws;                         // MPAD*1024 bf16
    ushort* wtq = xb  + (size_t)MPAD * DIMC;             // 3 contiguous = Wt_cat
    ushort* wtk = wtq + (size_t)DIMC * DIMC;
    ushort* wtv = wtk + (size_t)DIMC * DIMC;
    ushort* wtu = wtv + (size_t)DIMC * DIMC;
    ushort* kb  = wtu + (size_t)DIMC * DIMC;             // N*1024 bf16
    ushort* vb  = kb  + (size_t)N * DIMC;                // N*1024 bf16
    ushort* qb  = (ushort*)d_out;                        // q lives in d_out (bf16)
    ushort* ob  = xb;                                    // attn out reuses xb

    // fused preprocessing: 4 weight transposes + x cvt/pad in one launch
    prep_all<<<dim3(32, 32, 5), 256, 0, stream>>>(
        x, xb, N * DIMC, MPAD * DIMC, Wq, Wk, Wv, Wu, wtq, wtk, wtv, wtu);

    // fused QKV: 96 mt x 16 nt = 1536 blocks = 3 exact rounds at 2 blocks/CU
    gemm192<<<1536, 512, 0, stream>>>(xb, wtq, bq, bk, bv, qb, kb, vb, N);

    // attention: one 4-wave block per (b,h), identity order (load-balanced)
    attn_mfma<<<dim3(B * NHEAD), dim3(256), 0, stream>>>(qb, kb, vb, ob, lens, B);

    // final: 64 mt x 8 nt = 512 blocks = 1 exact round at 2 blocks/CU
    gemmF<<<512, 512, 0, stream>>>(ob, wtu, bu, (float*)d_out, N);
}

// Round 19
// 216.220 us; speedup vs baseline: 1.0482x; 1.0044x over previous
//
#include <hip/hip_runtime.h>
#include <hip/hip_bf16.h>
#include <math.h>

#define DIMC 1024
#define NHEAD 16
#define HDIM 64
#define MPAD 12288   // 12224 padded: 96*128, 64*192, 48*256

using bf16x8 = __attribute__((ext_vector_type(8))) short;
using f32x4  = __attribute__((ext_vector_type(4))) float;
using f32x16 = __attribute__((ext_vector_type(16))) float;

__device__ inline ushort f2bf(float f) {          // round-to-nearest-even
    uint u = __float_as_uint(f);
    u += 0x7fffu + ((u >> 16) & 1u);
    return (ushort)(u >> 16);
}
__device__ inline float bf2f(ushort h) { return __uint_as_float(((uint)h) << 16); }

__device__ inline uint pkbf(float a, float b) {   // pack 2 f32 -> 2 bf16 (lo=a)
    __hip_bfloat162 t = __float22bfloat162_rn(float2{a, b});
    return *reinterpret_cast<uint*>(&t);
}

__device__ inline void gload_lds16(const ushort* g, ushort* l) {
    __builtin_amdgcn_global_load_lds(
        (const __attribute__((address_space(1))) uint*)g,
        (__attribute__((address_space(3))) uint*)l, 16, 0, 0);
}

// ---------------------------------------------------------------------------
// QKV GEMM v2 (r13/r16/r18 verified: ~95-97us, MfmaUtil 34%, 2 blocks/CU):
// 128x192 tile, BK=64, 8 waves, LDS 80KB, grid 1536 = 3 exact rounds.
// ---------------------------------------------------------------------------
__global__ __launch_bounds__(512, 4) void gemm192(
    const ushort* __restrict__ A, const ushort* __restrict__ Bt,
    const float* __restrict__ bq, const float* __restrict__ bk,
    const float* __restrict__ bv,
    ushort* __restrict__ qb, ushort* __restrict__ kb, ushort* __restrict__ vb,
    int M)
{
    __shared__ ushort lds[2][(128 + 192) * 64];   // A at 0, B at 128*64 ushorts

    const int bid = blockIdx.x;
    const int xcd = bid & 7;
    const int j   = bid >> 3;                     // 0..191
    const int mt  = xcd * 12 + (j % 12);          // 0..95
    const int nt  = j / 12;                       // 0..15
    const int row0 = mt * 128;
    const int col0 = nt * 192;

    const int t512 = threadIdx.x;
    const int w    = t512 >> 6;
    const int lane = t512 & 63;
    const int wm   = w >> 2;                      // 0..1
    const int wn   = w & 3;                       // 0..3
    const int l15  = lane & 15;
    const int kh   = lane >> 4;                   // 0..3

    const int a0row = (w < 4) ? (w * 8) : (64 + (w - 4) * 8);   // qr0 rows
    const int a1row = a0row + 32;                                // qr1 rows

    auto stage = [&](int buf, int kt, int mat, int relRow) {
        const int o   = relRow * 128 + lane * 16;
        const int row = o >> 7;
        const int kb_ = (o & 127) ^ ((row & 7) << 4);
        const ushort* src = (mat ? Bt + (size_t)(col0 + row) * DIMC
                                 : A  + (size_t)(row0 + row) * DIMC)
                            + kt * 64 + (kb_ >> 1);
        gload_lds16(src, &lds[buf][0] + mat * (128 * 64) + relRow * 64);
    };
    auto rdA = [&](int buf, int rf, int ks) -> bf16x8 {
        const int row = wm * 64 + rf * 16 + l15;
        const int ad  = (row * 128 + ks * 64 + kh * 16) ^ ((row & 7) << 4);
        return *(const bf16x8*)(&lds[buf][0] + (ad >> 1));
    };
    auto rdB = [&](int buf, int n, int ks) -> bf16x8 {
        const int row = wn * 48 + n * 16 + l15;
        const int ad  = (row * 128 + ks * 64 + kh * 16) ^ ((row & 7) << 4);
        return *(const bf16x8*)(&lds[buf][128 * 64] + (ad >> 1));
    };

    f32x4 acc[4][3] = {};
    bf16x8 af[2][2];
    bf16x8 bf[3][2];

    stage(0, 0, 0, a0row);
    stage(0, 0, 1, w * 24);
    stage(0, 0, 1, w * 24 + 8);
    stage(0, 0, 1, w * 24 + 16);
    stage(0, 0, 0, a1row);

    const int NT = DIMC / 64;    // 16
    for (int t = 0; t < NT; ++t) {
        const int cur = t & 1;
        const int nxt = cur ^ 1;
        const int tn  = (t + 1 < NT) ? (t + 1) : (NT - 1);

        // -------- phase 0: qr0 (rf0,1) x all 48 cols --------
        asm volatile("s_waitcnt vmcnt(1)" ::: "memory");
        __builtin_amdgcn_s_barrier();
        __builtin_amdgcn_sched_barrier(0);
        #pragma unroll
        for (int rf = 0; rf < 2; ++rf)
            #pragma unroll
            for (int ks = 0; ks < 2; ++ks)
                af[rf][ks] = rdA(cur, rf, ks);
        #pragma unroll
        for (int n = 0; n < 3; ++n)
            #pragma unroll
            for (int ks = 0; ks < 2; ++ks)
                bf[n][ks] = rdB(cur, n, ks);
        stage(nxt, tn, 0, a0row);
        stage(nxt, tn, 1, w * 24);
        stage(nxt, tn, 1, w * 24 + 8);
        stage(nxt, tn, 1, w * 24 + 16);
        __builtin_amdgcn_s_setprio(1);
        #pragma unroll
        for (int rf = 0; rf < 2; ++rf)
            #pragma unroll
            for (int n = 0; n < 3; ++n)
                #pragma unroll
                for (int ks = 0; ks < 2; ++ks)
                    acc[rf][n] = __builtin_amdgcn_mfma_f32_16x16x32_bf16(
                        af[rf][ks], bf[n][ks], acc[rf][n], 0, 0, 0);
        __builtin_amdgcn_s_setprio(0);

        // -------- phase 1: qr1 (rf2,3) x all 48 cols --------
        asm volatile("s_waitcnt vmcnt(4)" ::: "memory");
        __builtin_amdgcn_s_barrier();
        __builtin_amdgcn_sched_barrier(0);
        #pragma unroll
        for (int rf = 0; rf < 2; ++rf)
            #pragma unroll
            for (int ks = 0; ks < 2; ++ks)
                af[rf][ks] = rdA(cur, 2 + rf, ks);
        stage(nxt, tn, 0, a1row);
        __builtin_amdgcn_s_setprio(1);
        #pragma unroll
        for (int rf = 0; rf < 2; ++rf)
            #pragma unroll
            for (int n = 0; n < 3; ++n)
                #pragma unroll
                for (int ks = 0; ks < 2; ++ks)
                    acc[2 + rf][n] = __builtin_amdgcn_mfma_f32_16x16x32_bf16(
                        af[rf][ks], bf[n][ks], acc[2 + rf][n], 0, 0, 0);
        __builtin_amdgcn_s_setprio(0);
    }

    #pragma unroll
    for (int n = 0; n < 3; ++n) {
        const int cg = col0 + wn * 48 + n * 16 + l15;
        const int s  = cg >> 10;
        const int cb = cg & 1023;
        const float bb = ((s == 0) ? bq : (s == 1) ? bk : bv)[cb];
        ushort* op     = (s == 0) ? qb : (s == 1) ? kb : vb;
        #pragma unroll
        for (int i = 0; i < 4; ++i) {
            #pragma unroll
            for (int r = 0; r < 4; ++r) {
                const int gr = row0 + wm * 64 + i * 16 + kh * 4 + r;
                if (gr < M)
                    op[(size_t)gr * DIMC + cb] = f2bf(acc[i][n][r] + bb);
            }
        }
    }
}

// ---------------------------------------------------------------------------
// Final GEMM v4 (r16/r18 verified): 192x128 tile, symmetric counted ledger,
// 2 blocks/CU, grid 512 = 1 exact round.
// ---------------------------------------------------------------------------
__global__ __launch_bounds__(512, 4) void gemmF(
    const ushort* __restrict__ A, const ushort* __restrict__ Bt,
    const float* __restrict__ bias, float* __restrict__ C, int M)
{
    __shared__ ushort lds[2][(192 + 128) * 64];   // A at 0, B at 192*64 ushorts

    const int bid = blockIdx.x;
    const int xcd = bid & 7;
    const int j   = bid >> 3;                     // 0..63
    const int mt  = xcd * 8 + (j % 8);            // 0..63
    const int nt  = j / 8;                        // 0..7
    const int row0 = mt * 192;
    const int col0 = nt * 128;

    const int t512 = threadIdx.x;
    const int w    = t512 >> 6;
    const int lane = t512 & 63;
    const int wm   = w >> 1;                      // 0..3
    const int wn   = w & 1;                       // 0..1
    const int l15  = lane & 15;
    const int kh   = lane >> 4;                   // 0..3

    auto stage = [&](int buf, int kt, int mat, int relRow) {
        const int o   = relRow * 128 + lane * 16;
        const int row = o >> 7;
        const int kb_ = (o & 127) ^ ((row & 7) << 4);
        const ushort* src = (mat ? Bt + (size_t)(col0 + row) * DIMC
                                 : A  + (size_t)(row0 + row) * DIMC)
                            + kt * 64 + (kb_ >> 1);
        gload_lds16(src, &lds[buf][0] + mat * (192 * 64) + relRow * 64);
    };
    auto rdA = [&](int buf, int rf, int ks) -> bf16x8 {
        const int row = wm * 48 + rf * 16 + l15;
        const int ad  = (row * 128 + ks * 64 + kh * 16) ^ ((row & 7) << 4);
        return *(const bf16x8*)(&lds[buf][0] + (ad >> 1));
    };
    auto rdB = [&](int buf, int n, int ks) -> bf16x8 {
        const int row = wn * 64 + n * 16 + l15;
        const int ad  = (row * 128 + ks * 64 + kh * 16) ^ ((row & 7) << 4);
        return *(const bf16x8*)(&lds[buf][192 * 64] + (ad >> 1));
    };

    f32x4 acc[3][4] = {};
    bf16x8 af[2];           // current row-frag (2 ks)
    bf16x8 bf[4][2];        // all 4 col-frags, read once per K-tile

    const int aP0 = wm * 48 + wn * 8;        // phase-0 A chunk
    const int aP1 = aP0 + 16;                // phase-1 A chunk
    const int aP2 = aP0 + 32;                // phase-2 A chunk

    // prologue: tile 0 -> buf 0, slot order B0 B1 a0 a1 a2
    stage(0, 0, 1, w * 16);
    stage(0, 0, 1, w * 16 + 8);
    stage(0, 0, 0, aP0);
    stage(0, 0, 0, aP1);
    stage(0, 0, 0, aP2);

    const int NT = DIMC / 64;    // 16
    for (int t = 0; t < NT; ++t) {
        const int cur = t & 1;
        const int nxt = cur ^ 1;
        const int tn  = (t + 1 < NT) ? (t + 1) : (NT - 1);   // last iter: dead restage

        // -------- phase 0: rf0 x all 64 cols --------
        asm volatile("s_waitcnt vmcnt(2)" ::: "memory");
        __builtin_amdgcn_s_barrier();
        __builtin_amdgcn_sched_barrier(0);
        #pragma unroll
        for (int ks = 0; ks < 2; ++ks)
            af[ks] = rdA(cur, 0, ks);
        #pragma unroll
        for (int n = 0; n < 4; ++n)
            #pragma unroll
            for (int ks = 0; ks < 2; ++ks)
                bf[n][ks] = rdB(cur, n, ks);
        stage(nxt, tn, 1, w * 16);
        stage(nxt, tn, 1, w * 16 + 8);
        stage(nxt, tn, 0, aP0);
        __builtin_amdgcn_s_setprio(1);
        #pragma unroll
        for (int n = 0; n < 4; ++n)
            #pragma unroll
            for (int ks = 0; ks < 2; ++ks)
                acc[0][n] = __builtin_amdgcn_mfma_f32_16x16x32_bf16(
                    af[ks], bf[n][ks], acc[0][n], 0, 0, 0);
        __builtin_amdgcn_s_setprio(0);

        // -------- phase 1: rf1 --------
        asm volatile("s_waitcnt vmcnt(4)" ::: "memory");
        __builtin_amdgcn_s_barrier();
        __builtin_amdgcn_sched_barrier(0);
        #pragma unroll
        for (int ks = 0; ks < 2; ++ks)
            af[ks] = rdA(cur, 1, ks);
        stage(nxt, tn, 0, aP1);
        __builtin_amdgcn_s_setprio(1);
        #pragma unroll
        for (int n = 0; n < 4; ++n)
            #pragma unroll
            for (int ks = 0; ks < 2; ++ks)
                acc[1][n] = __builtin_amdgcn_mfma_f32_16x16x32_bf16(
                    af[ks], bf[n][ks], acc[1][n], 0, 0, 0);
        __builtin_amdgcn_s_setprio(0);

        // -------- phase 2: rf2 --------
        asm volatile("s_waitcnt vmcnt(4)" ::: "memory");
        __builtin_amdgcn_s_barrier();
        __builtin_amdgcn_sched_barrier(0);
        #pragma unroll
        for (int ks = 0; ks < 2; ++ks)
            af[ks] = rdA(cur, 2, ks);
        stage(nxt, tn, 0, aP2);
        __builtin_amdgcn_s_setprio(1);
        #pragma unroll
        for (int n = 0; n < 4; ++n)
            #pragma unroll
            for (int ks = 0; ks < 2; ++ks)
                acc[2][n] = __builtin_amdgcn_mfma_f32_16x16x32_bf16(
                    af[ks], bf[n][ks], acc[2][n], 0, 0, 0);
        __builtin_amdgcn_s_setprio(0);
    }

    // epilogue
    #pragma unroll
    for (int n = 0; n < 4; ++n) {
        const int c  = col0 + wn * 64 + n * 16 + l15;
        const float bb = bias[c];
        #pragma unroll
        for (int i = 0; i < 3; ++i) {
            #pragma unroll
            for (int r = 0; r < 4; ++r) {
                const int gr = row0 + wm * 48 + i * 16 + kh * 4 + r;
                if (gr < M)
                    C[(size_t)gr * DIMC + c] = acc[i][n][r] + bb;
            }
        }
    }
}

// ---------------------------------------------------------------------------
// Fused preprocessing: z=0..3 -> transpose+cvt W[z]; z=4 -> cvt+pad x.
// ---------------------------------------------------------------------------
__global__ __launch_bounds__(256) void prep_all(
    const float* __restrict__ x, ushort* __restrict__ xb, int nvalid, int ntot,
    const float* __restrict__ W0, const float* __restrict__ W1,
    const float* __restrict__ W2, const float* __restrict__ W3,
    ushort* __restrict__ T0, ushort* __restrict__ T1,
    ushort* __restrict__ T2, ushort* __restrict__ T3)
{
    __shared__ float tile[32][33];
    const int z = blockIdx.z;
    if (z == 4) {
        const int bidf  = blockIdx.y * 32 + blockIdx.x;      // 0..1023
        const int start = bidf * 256 + threadIdx.x;
        const int stride = 1024 * 256;
        for (int i = start; i < ntot / 4; i += stride) {
            const int e = i * 4;
            ushort4 o;
            if (e < nvalid) {
                const float4 f = *(const float4*)(x + e);
                o.x = f2bf(f.x); o.y = f2bf(f.y); o.z = f2bf(f.z); o.w = f2bf(f.w);
            } else { o.x = o.y = o.z = o.w = 0; }
            *(ushort4*)(xb + e) = o;
        }
        return;
    }
    const float* W = (z == 0) ? W0 : (z == 1) ? W1 : (z == 2) ? W2 : W3;
    ushort*      T = (z == 0) ? T0 : (z == 1) ? T1 : (z == 2) ? T2 : T3;
    const int tx = threadIdx.x & 31;
    const int ty = threadIdx.x >> 5;
    const int n0 = blockIdx.x * 32;
    const int k0 = blockIdx.y * 32;
    #pragma unroll
    for (int i = 0; i < 32; i += 8)
        tile[ty + i][tx] = W[(size_t)(k0 + ty + i) * DIMC + n0 + tx];
    __syncthreads();
    #pragma unroll
    for (int i = 0; i < 32; i += 8)
        T[(size_t)(n0 + ty + i) * DIMC + k0 + tx] = f2bf(tile[tx][ty + i]);
}

// ---------------------------------------------------------------------------
// MFMA flash attention v5: one 256-thread block per (b,h), identity block
// mapping (r18 verified: load-balanced).  exp2-domain softmax; defer-max
// threshold raised 4 -> 8 (T13/HK value; p <= 2^8, bf16-P + fp32 l/o have
// headroom; rescale passes drop to ~0-1 per segment).
// ---------------------------------------------------------------------------
__global__ __launch_bounds__(256) void attn_mfma(
    const ushort* __restrict__ qg, const ushort* __restrict__ kg,
    const ushort* __restrict__ vg, ushort* __restrict__ og,
    const int* __restrict__ lens, int B)
{
    __shared__ ushort Kt[2][64 * 64];   // swizzled K tiles (8KB each)
    __shared__ ushort Vt[64 * 68];      // V^T, row stride 68 ushorts

    const int bh = blockIdx.x;          // identity mapping (load balance)
    const int h  = bh & 15;
    const int b  = bh >> 4;

    const int tid  = threadIdx.x;
    const int qt   = tid >> 6;
    const int lane = tid & 63;

    const int myl = (lane < B) ? lens[lane] : 0;
    int inc = myl;
    #pragma unroll
    for (int d = 1; d < 64; d <<= 1) {
        const int nb = __shfl_up(inc, d);
        if (lane >= d) inc += nb;
    }
    const int off = __shfl(inc, b) - __shfl(myl, b);
    const int L   = __shfl(myl, b);
    const int ntk = (L + 63) >> 6;
    const bool active = (qt * 64 < L);

    const int l31 = lane & 31;
    const int hi  = lane >> 5;

    // Q fragments with scale*(log2 e) folded in: scores land in log2 domain.
    const float QSCALE = 0.03125f * 1.44269504f;
    bf16x8 qf[2][4];
    if (active) {
        #pragma unroll
        for (int qn = 0; qn < 2; ++qn) {
            const size_t row = (size_t)(off + min(qt * 64 + qn * 32 + l31, L - 1));
            #pragma unroll
            for (int ks = 0; ks < 4; ++ks) {
                union { uint4 u4; ushort us[8]; bf16x8 v; } tmp;
                tmp.u4 = *(const uint4*)(qg + row * DIMC + h * HDIM + ks * 16 + hi * 8);
                #pragma unroll
                for (int e = 0; e < 8; ++e)
                    tmp.us[e] = f2bf(bf2f(tmp.us[e]) * QSCALE);
                qf[qn][ks] = tmp.v;
            }
        }
    }

    auto stageK = [&](int tt, int buf) {
        #pragma unroll
        for (int u0 = 0; u0 < 2; ++u0) {
            const int u   = tid + u0 * 256;
            const int o   = u * 16;
            const int row = o >> 7;
            const int kb_ = (o & 127) ^ ((row & 7) << 4);
            const ushort* src = kg + (size_t)(off + min(tt * 64 + row, L - 1)) * DIMC
                                + h * HDIM + (kb_ >> 1);
            gload_lds16(src, &Kt[buf][0] + u * 8);
        }
    };

    const int pr   = lane & 7;
    const int doct = lane >> 3;
    const int d0v  = doct * 8;
    uint4 v0, v1;
    auto loadV = [&](int tt) {
        const int k0 = tt * 64 + qt * 16 + 2 * pr;
        v0 = *(const uint4*)(vg + (size_t)(off + min(k0,     L - 1)) * DIMC + h * HDIM + d0v);
        v1 = *(const uint4*)(vg + (size_t)(off + min(k0 + 1, L - 1)) * DIMC + h * HDIM + d0v);
    };

    stageK(0, 0);
    loadV(0);

    f32x16 o[2][2] = {};
    float mst[2] = {-1e30f, -1e30f};
    float lst[2] = {0.f, 0.f};

    for (int t = 0; t < ntk; ++t) {
        const int cur = t & 1;
        const int j0  = t * 64;
        const int tn  = (t + 1 < ntk) ? (t + 1) : (ntk - 1);

        stageK(tn, cur ^ 1);
        asm volatile("s_waitcnt vmcnt(2)" ::: "memory");
        __builtin_amdgcn_s_barrier();
        __builtin_amdgcn_sched_barrier(0);

        f32x16 s[2][2] = {};
        if (active) {
            bf16x8 kf[2][4];
            #pragma unroll
            for (int km = 0; km < 2; ++km) {
                const int row = km * 32 + l31;
                #pragma unroll
                for (int ks = 0; ks < 4; ++ks) {
                    const int ad = (row * 128 + ks * 32 + hi * 16) ^ ((row & 7) << 4);
                    kf[km][ks] = *(const bf16x8*)(&Kt[cur][0] + (ad >> 1));
                }
            }
            __builtin_amdgcn_s_setprio(1);
            #pragma unroll
            for (int km = 0; km < 2; ++km)
                #pragma unroll
                for (int qn = 0; qn < 2; ++qn)
                    #pragma unroll
                    for (int ks = 0; ks < 4; ++ks)
                        s[km][qn] = __builtin_amdgcn_mfma_f32_32x32x16_bf16(
                            kf[km][ks], qf[qn][ks], s[km][qn], 0, 0, 0);
            __builtin_amdgcn_s_setprio(0);
        }

        {
            const uint a4[4] = {v0.x, v0.y, v0.z, v0.w};
            const uint b4[4] = {v1.x, v1.y, v1.z, v1.w};
            const int  col   = qt * 16 + 2 * pr;
            #pragma unroll
            for (int jj = 0; jj < 4; ++jj) {
                const uint lo  = (a4[jj] & 0xffffu) | (b4[jj] << 16);
                const uint hi2 = (a4[jj] >> 16) | (b4[jj] & 0xffff0000u);
                *(uint*)&Vt[(d0v + 2 * jj)     * 68 + col] = lo;
                *(uint*)&Vt[(d0v + 2 * jj + 1) * 68 + col] = hi2;
            }
        }
        if (t + 1 < ntk) loadV(t + 1);

        if (active) {
            const bool fullTile = (j0 + 64 <= L);
            float tmv[2];
            #pragma unroll
            for (int qn = 0; qn < 2; ++qn) {
                float tm = -1e30f;
                if (fullTile) {
                    #pragma unroll
                    for (int km = 0; km < 2; ++km)
                        #pragma unroll
                        for (int r = 0; r < 16; ++r)
                            tm = fmaxf(tm, s[km][qn][r]);
                } else {
                    #pragma unroll
                    for (int km = 0; km < 2; ++km)
                        #pragma unroll
                        for (int r = 0; r < 16; ++r) {
                            const int key = j0 + km * 32 + (r & 3) + 8 * (r >> 2) + 4 * hi;
                            float sv = s[km][qn][r];
                            sv = (key < L) ? sv : -1e30f;
                            s[km][qn][r] = sv;
                            tm = fmaxf(tm, sv);
                        }
                }
                tm = fmaxf(tm, __shfl_xor(tm, 32));
                tmv[qn] = tm;
            }

            // defer-max in log2 units: skip rescale while p <= 2^8 (T13 THR=8)
            const bool need = (tmv[0] > mst[0] + 8.f) || (tmv[1] > mst[1] + 8.f);
            if (__any(need)) {
                #pragma unroll
                for (int qn = 0; qn < 2; ++qn) {
                    const float nm = fmaxf(mst[qn], tmv[qn]);
                    const float corr = exp2f(mst[qn] - nm);
                    mst[qn] = nm;
                    lst[qn] *= corr;
                    #pragma unroll
                    for (int dm = 0; dm < 2; ++dm)
                        #pragma unroll
                        for (int r = 0; r < 16; ++r)
                            o[dm][qn][r] *= corr;
                }
            }
            #pragma unroll
            for (int qn = 0; qn < 2; ++qn) {
                float ls = 0.f;
                #pragma unroll
                for (int km = 0; km < 2; ++km)
                    #pragma unroll
                    for (int r = 0; r < 16; ++r) {
                        const float p = exp2f(s[km][qn][r] - mst[qn]);
                        s[km][qn][r] = p;
                        ls += p;
                    }
                ls += __shfl_xor(ls, 32);
                lst[qn] += ls;
            }
        }

        asm volatile("s_waitcnt lgkmcnt(0)" ::: "memory");
        __builtin_amdgcn_s_barrier();
        __builtin_amdgcn_sched_barrier(0);

        if (active) {
            #pragma unroll
            for (int kspv = 0; kspv < 4; ++kspv) {
                const int km = kspv >> 1;
                const int sb = kspv & 1;

                bf16x8 Afr[2];
                #pragma unroll
                for (int dm = 0; dm < 2; ++dm) {
                    const int d = dm * 32 + l31;
                    const uint2 p0 = *(const uint2*)&Vt[d * 68 + kspv * 16 + hi * 8];
                    const uint2 p1 = *(const uint2*)&Vt[d * 68 + kspv * 16 + hi * 8 + 4];
                    union { uint u[4]; bf16x8 v; } aa;
                    aa.u[0] = p0.x; aa.u[1] = p0.y; aa.u[2] = p1.x; aa.u[3] = p1.y;
                    Afr[dm] = aa.v;
                }

                bf16x8 Bfr[2];
                #pragma unroll
                for (int qn = 0; qn < 2; ++qn) {
                    const uint X0 = pkbf(s[km][qn][8 * sb + 0], s[km][qn][8 * sb + 1]);
                    const uint X1 = pkbf(s[km][qn][8 * sb + 2], s[km][qn][8 * sb + 3]);
                    const uint Y0 = pkbf(s[km][qn][8 * sb + 4], s[km][qn][8 * sb + 5]);
                    const uint Y1 = pkbf(s[km][qn][8 * sb + 6], s[km][qn][8 * sb + 7]);
                    const uint sx0 = (uint)__shfl_xor((int)X0, 32);
                    const uint sx1 = (uint)__shfl_xor((int)X1, 32);
                    const uint sy0 = (uint)__shfl_xor((int)Y0, 32);
                    const uint sy1 = (uint)__shfl_xor((int)Y1, 32);
                    union { uint u[4]; bf16x8 v; } bb;
                    bb.u[0] = hi ? sy0 : X0;
                    bb.u[1] = hi ? sy1 : X1;
                    bb.u[2] = hi ? Y0 : sx0;
                    bb.u[3] = hi ? Y1 : sx1;
                    Bfr[qn] = bb.v;
                }

                __builtin_amdgcn_s_setprio(1);
                #pragma unroll
                for (int dm = 0; dm < 2; ++dm)
                    #pragma unroll
                    for (int qn = 0; qn < 2; ++qn)
                        o[dm][qn] = __builtin_amdgcn_mfma_f32_32x32x16_bf16(
                            Afr[dm], Bfr[qn], o[dm][qn], 0, 0, 0);
                __builtin_amdgcn_s_setprio(0);
            }
        }
    }

    if (active) {
        #pragma unroll
        for (int qn = 0; qn < 2; ++qn) {
            const int q = qt * 64 + qn * 32 + l31;
            if (q < L) {
                const float inv = 1.f / lst[qn];
                ushort* orow = og + (size_t)(off + q) * DIMC + h * HDIM;
                #pragma unroll
                for (int dm = 0; dm < 2; ++dm)
                    #pragma unroll
                    for (int bq2 = 0; bq2 < 4; ++bq2) {
                        const int r0 = 4 * bq2;
                        uint2 st;
                        st.x = pkbf(o[dm][qn][r0 + 0] * inv, o[dm][qn][r0 + 1] * inv);
                        st.y = pkbf(o[dm][qn][r0 + 2] * inv, o[dm][qn][r0 + 3] * inv);
                        *(uint2*)(orow + dm * 32 + 8 * bq2 + 4 * hi) = st;
                    }
            }
        }
    }
}

// ---------------------------------------------------------------------------
extern "C" void kernel_launch(void* const* d_in, const int* in_sizes, int n_in,
                              void* d_out, int out_size, void* d_ws, size_t ws_size,
                              hipStream_t stream)
{
    const float* x   = (const float*)d_in[0];
    const float* Wq  = (const float*)d_in[1];
    const float* bq  = (const float*)d_in[2];
    const float* Wk  = (const float*)d_in[3];
    const float* bk  = (const float*)d_in[4];
    const float* Wv  = (const float*)d_in[5];
    const float* bv  = (const float*)d_in[6];
    const float* Wu  = (const float*)d_in[7];
    const float* bu  = (const float*)d_in[8];
    const int*  lens = (const int*)d_in[9];

    const int N = in_sizes[0] / DIMC;    // 12224
    const int B = in_sizes[9];           // 64

    ushort* xb  = (ushort*)d_ws;                         // MPAD*1024 bf16
    ushort* wtq = xb  + (size_t)MPAD * DIMC;             // 3 contiguous = Wt_cat
    ushort* wtk = wtq + (size_t)DIMC * DIMC;
    ushort* wtv = wtk + (size_t)DIMC * DIMC;
    ushort* wtu = wtv + (size_t)DIMC * DIMC;
    ushort* kb  = wtu + (size_t)DIMC * DIMC;             // N*1024 bf16
    ushort* vb  = kb  + (size_t)N * DIMC;                // N*1024 bf16
    ushort* qb  = (ushort*)d_out;                        // q lives in d_out (bf16)
    ushort* ob  = xb;                                    // attn out reuses xb

    // fused preprocessing: 4 weight transposes + x cvt/pad in one launch
    prep_all<<<dim3(32, 32, 5), 256, 0, stream>>>(
        x, xb, N * DIMC, MPAD * DIMC, Wq, Wk, Wv, Wu, wtq, wtk, wtv, wtu);

    // fused QKV: 96 mt x 16 nt = 1536 blocks = 3 exact rounds at 2 blocks/CU
    gemm192<<<1536, 512, 0, stream>>>(xb, wtq, bq, bk, bv, qb, kb, vb, N);

    // attention: one 4-wave block per (b,h), identity order (load-balanced)
    attn_mfma<<<dim3(B * NHEAD), dim3(256), 0, stream>>>(qb, kb, vb, ob, lens, B);

    // final: 64 mt x 8 nt = 512 blocks = 1 exact round at 2 blocks/CU
    gemmF<<<512, 512, 0, stream>>>(ob, wtu, bu, (float*)d_out, N);
}